// Round 1
// 565.057 us; speedup vs baseline: 1.1337x; 1.1337x over previous
//
#include <hip/hip_runtime.h>
#include <cstdint>
#include <cstddef>

typedef __bf16 bf16;
typedef __bf16 bf16x8 __attribute__((ext_vector_type(8)));
typedef __bf16 bf16v4 __attribute__((ext_vector_type(4)));
typedef float  f32x4  __attribute__((ext_vector_type(4)));

// Problem constants: B=128, N=49, G=4096, H=1024, A=1024
#define PB   128
#define PN   49
#define PG   4096
#define PH   1024
#define PA   1024
#define PM1  (PB * PN)   // 6272

// ---------------------------------------------------------------------------
// dtype detect: flag=1 -> bf16 inputs, 0 -> fp32.
// ---------------------------------------------------------------------------
__global__ __launch_bounds__(256) void detect_kernel(
    const unsigned short* __restrict__ raw, int* __restrict__ flag)
{
    __shared__ int cnt;
    if (threadIdx.x == 0) cnt = 0;
    __syncthreads();
    unsigned short u = raw[threadIdx.x];
    float x = __uint_as_float(((unsigned int)u) << 16);
    float a = fabsf(x);
    atomicAdd(&cnt, (a >= 1e-7f && a <= 128.f) ? 1 : 0);
    __syncthreads();
    if (threadIdx.x == 0) flag[0] = (cnt >= 200) ? 1 : 0;
}

__device__ __forceinline__ float ldin(const void* p, size_t i, bool in32) {
    return in32 ? ((const float*)p)[i] : (float)((const bf16*)p)[i];
}

// raw (flag dtype) -> bf16, 8 elems/thread
__global__ __launch_bounds__(256) void cvt_kernel(
    const void* __restrict__ in, const int* __restrict__ flag,
    bf16* __restrict__ out)
{
    const bool in32 = (flag[0] == 0);
    size_t i = ((size_t)blockIdx.x * 256 + threadIdx.x) * 8;
    bf16x8 o;
    if (in32) {
        f32x4 lo = *(const f32x4*)((const float*)in + i);
        f32x4 hi = *(const f32x4*)((const float*)in + i + 4);
#pragma unroll
        for (int j = 0; j < 4; ++j) { o[j] = (bf16)lo[j]; o[4 + j] = (bf16)hi[j]; }
    } else {
        o = *(const bf16x8*)((const bf16*)in + i);
    }
    *(bf16x8*)(out + i) = o;
}

// ---------------------------------------------------------------------------
// GEMM: C[M,N] = A[M,K] @ (Bt0 [+ Bt1])^T.  128x128 tile, BK=64, 4 waves,
// mfma 16x16x32 bf16.  All operands bf16, staged via global_load_lds(16B)
// async DMA (dest = wave-uniform base + lane*16) with a (chunk+row)&7
// rotation applied on the SOURCE address so frag ds_read_b128 spreads over
// all 8 bank groups (bank-conflict free, verified 0 in prior rocprof).
// NEW: bijective XCD-aware block swizzle (guide m204) — each XCD owns a
// contiguous flat-id chunk, so the A row-panel shared by the gx consecutive
// n-blocks is fetched into one XCD's L2 once instead of 8 XCDs re-fetching.
// Split-K via bz plane (fp32 Cf or bf16 Cb per BF16OUT).
// ---------------------------------------------------------------------------
template <int BF16OUT, int AADAPT, int BTERMS>
__global__ __launch_bounds__(256, 2) void gemm_kernel(
    const void* __restrict__ Araw, const bf16* __restrict__ Bt0,
    const bf16* __restrict__ Bt1, const int* __restrict__ flag,
    float* __restrict__ Cf, bf16* __restrict__ Cb,
    int M, int N, int K, int kTilesPerSplit)
{
    __shared__ __align__(16) bf16 lds[(BTERMS == 2 ? 3 : 2) * 128 * 64];
    bf16* As  = lds;
    bf16* Bs0 = lds + 128 * 64;
    bf16* Bs1 = lds + 2 * 128 * 64;

    const bool a32 = AADAPT && (flag[0] == 0);

    // ---- bijective XCD swizzle of the flattened block id ----
    const int gx = gridDim.x, gy = gridDim.y;
    const int nwg = gx * gy * (int)gridDim.z;
    int flat = blockIdx.x + gx * (blockIdx.y + gy * blockIdx.z);
    {
        const int q8 = nwg >> 3, r8 = nwg & 7;
        const int xcd = flat & 7, sub = flat >> 3;
        flat = (xcd < r8 ? xcd * (q8 + 1) : r8 * (q8 + 1) + (xcd - r8) * q8) + sub;
    }
    const int bx  = flat % gx;
    const int byz = flat / gx;
    const int by  = byz % gy;
    const int bz  = byz / gy;

    const int tid  = threadIdx.x;
    const int m0   = by * 128;
    const int n0   = bx * 128;
    const int kt0  = bz * kTilesPerSplit;

    const int wave = tid >> 6;
    const int lane = tid & 63;
    const int wm   = (wave >> 1) * 64;
    const int wn   = (wave & 1) * 64;
    const int lm   = lane & 15;
    const int q    = lane >> 4;

    f32x4 acc[4][4];
#pragma unroll
    for (int i = 0; i < 4; ++i)
#pragma unroll
        for (int j = 0; j < 4; ++j) acc[i][j] = (f32x4)0.0f;

    for (int kt = 0; kt < kTilesPerSplit; ++kt) {
        const int k0 = (kt0 + kt) * 64;
#pragma unroll
        for (int it = 0; it < 4; ++it) {
            int p   = it * 256 + tid;
            int row = p >> 3;
            int lc  = ((p & 7) - row) & 7;       // logical chunk held by phys slot p
            size_t offB = (size_t)(n0 + row) * K + k0 + lc * 8;
            __builtin_amdgcn_global_load_lds((void*)(Bt0 + offB), (void*)(Bs0 + p * 8), 16, 0, 0);
            if (BTERMS == 2)
                __builtin_amdgcn_global_load_lds((void*)(Bt1 + offB), (void*)(Bs1 + p * 8), 16, 0, 0);
            size_t offA = (size_t)(m0 + row) * K + k0 + lc * 8;
            if (AADAPT) {
                bf16x8 va;
                if (a32) {
                    const float* pf = (const float*)Araw + offA;
                    f32x4 lo = *(const f32x4*)pf, hi = *(const f32x4*)(pf + 4);
#pragma unroll
                    for (int j = 0; j < 4; ++j) { va[j] = (bf16)lo[j]; va[4 + j] = (bf16)hi[j]; }
                } else {
                    va = *(const bf16x8*)((const bf16*)Araw + offA);
                }
                *(bf16x8*)(As + p * 8) = va;
            } else {
                __builtin_amdgcn_global_load_lds((void*)((const bf16*)Araw + offA),
                                                 (void*)(As + p * 8), 16, 0, 0);
            }
        }
        __syncthreads();

#pragma unroll
        for (int s = 0; s < 2; ++s) {
            bf16x8 af[4], bf0[4], bf1[4];
            const int c = s * 4 + q;
#pragma unroll
            for (int mi = 0; mi < 4; ++mi) {
                int row  = wm + mi * 16 + lm;
                int slot = row * 8 + ((c + row) & 7);
                af[mi] = *(const bf16x8*)(As + slot * 8);
            }
#pragma unroll
            for (int ni = 0; ni < 4; ++ni) {
                int row  = wn + ni * 16 + lm;
                int slot = row * 8 + ((c + row) & 7);
                bf0[ni] = *(const bf16x8*)(Bs0 + slot * 8);
                if (BTERMS == 2) bf1[ni] = *(const bf16x8*)(Bs1 + slot * 8);
            }
#pragma unroll
            for (int mi = 0; mi < 4; ++mi)
#pragma unroll
                for (int ni = 0; ni < 4; ++ni) {
                    acc[mi][ni] = __builtin_amdgcn_mfma_f32_16x16x32_bf16(
                        af[mi], bf0[ni], acc[mi][ni], 0, 0, 0);
                    if (BTERMS == 2)
                        acc[mi][ni] = __builtin_amdgcn_mfma_f32_16x16x32_bf16(
                            af[mi], bf1[ni], acc[mi][ni], 0, 0, 0);
                }
        }
        __syncthreads();
    }

#pragma unroll
    for (int mi = 0; mi < 4; ++mi)
#pragma unroll
        for (int ni = 0; ni < 4; ++ni)
#pragma unroll
            for (int r = 0; r < 4; ++r) {
                int row = m0 + wm + mi * 16 + q * 4 + r;
                int col = n0 + wn + ni * 16 + lm;
                if (BF16OUT)
                    Cb[(size_t)bz * M * N + (size_t)row * N + col] = (bf16)acc[mi][ni][r];
                else
                    Cf[(size_t)bz * M * N + (size_t)row * N + col] = acc[mi][ni][r];
            }
}

// ---------------------------------------------------------------------------
// Transpose [R,C]->[C,R] bf16 out from raw input (dtype per flag).
// grid (C/64, R/64).
// ---------------------------------------------------------------------------
__global__ __launch_bounds__(256) void transpose_kernel(
    const void* __restrict__ in, const int* __restrict__ flag, int inMode,
    bf16* __restrict__ out, int R, int C)
{
    __shared__ bf16 tile[64][65];
    const bool in32 = (inMode == 0) && (flag[0] == 0);
    const int r0 = blockIdx.y * 64, c0 = blockIdx.x * 64;
    const int tx = threadIdx.x & 15, ty = threadIdx.x >> 4;
#pragma unroll
    for (int it = 0; it < 4; ++it) {
        int r = it * 16 + ty;
        size_t base = (size_t)(r0 + r) * C + c0 + tx * 4;
        if (in32) {
            f32x4 v = *(const f32x4*)((const float*)in + base);
#pragma unroll
            for (int i = 0; i < 4; ++i) tile[r][tx * 4 + i] = (bf16)v[i];
        } else {
            bf16v4 v = *(const bf16v4*)((const bf16*)in + base);
#pragma unroll
            for (int i = 0; i < 4; ++i) tile[r][tx * 4 + i] = v[i];
        }
    }
    __syncthreads();
#pragma unroll
    for (int it = 0; it < 4; ++it) {
        int c = it * 16 + ty;
        bf16v4 v;
#pragma unroll
        for (int i = 0; i < 4; ++i) v[i] = tile[tx * 4 + i][c];
        *(bf16v4*)(out + (size_t)(c0 + c) * R + r0 + tx * 4) = v;
    }
}

// ---------------------------------------------------------------------------
// Fused split-K reduce (2 bf16 planes) + transpose.
// in: two bf16 planes [R,C] at in and in+R*C.  outT[C,R] = (p0+p1)^T.
// WRITEN: also write outN[R,C] = p0+p1 (non-transposed).  grid (C/64, R/64).
// Replaces the standalone reduce pass + transpose pass of R3.
// ---------------------------------------------------------------------------
template <int WRITEN>
__global__ __launch_bounds__(256) void transpose_red2_kernel(
    const bf16* __restrict__ in, bf16* __restrict__ outT,
    bf16* __restrict__ outN, int R, int C)
{
    __shared__ bf16 tile[64][65];
    const size_t plane = (size_t)R * C;
    const int r0 = blockIdx.y * 64, c0 = blockIdx.x * 64;
    const int tx = threadIdx.x & 15, ty = threadIdx.x >> 4;
#pragma unroll
    for (int it = 0; it < 4; ++it) {
        int r = it * 16 + ty;
        size_t base = (size_t)(r0 + r) * C + c0 + tx * 4;
        bf16v4 va = *(const bf16v4*)(in + base);
        bf16v4 vb = *(const bf16v4*)(in + plane + base);
        bf16v4 s4;
#pragma unroll
        for (int i = 0; i < 4; ++i) {
            s4[i] = (bf16)((float)va[i] + (float)vb[i]);
            tile[r][tx * 4 + i] = s4[i];
        }
        if (WRITEN) *(bf16v4*)(outN + base) = s4;
    }
    __syncthreads();
#pragma unroll
    for (int it = 0; it < 4; ++it) {
        int c = it * 16 + ty;
        bf16v4 v;
#pragma unroll
        for (int i = 0; i < 4; ++i) v[i] = tile[tx * 4 + i][c];
        *(bf16v4*)(outT + (size_t)(c0 + c) * R + r0 + tx * 4) = v;
    }
}

// matvec: part[zy][c] = sum_{r in slice} x[r]*W[r,c]
__global__ __launch_bounds__(256) void matvec_part_kernel(
    const void* __restrict__ x, const void* __restrict__ W,
    const int* __restrict__ flag, int xMode,
    float* __restrict__ part, int C, int rPer)
{
    const bool in32 = (flag[0] == 0);
    int c  = blockIdx.x * 256 + threadIdx.x;
    int r0 = blockIdx.y * rPer;
    float acc = 0.f;
    for (int r = r0; r < r0 + rPer; ++r) {
        float xv = (xMode == 0) ? ((const float*)x)[r] : ldin(x, r, in32);
        acc += xv * ldin(W, (size_t)r * C + c, in32);
    }
    part[(size_t)blockIdx.y * C + c] = acc;
}

__global__ __launch_bounds__(256) void matvec_fin_kernel(
    const float* __restrict__ part, const void* __restrict__ addv,
    const int* __restrict__ flag, float* __restrict__ y, int S, int C)
{
    const bool in32 = (flag[0] == 0);
    int c = blockIdx.x * 256 + threadIdx.x;
    float acc = addv ? ldin(addv, c, in32) : 0.f;
    for (int s = 0; s < S; ++s) acc += part[(size_t)s * C + c];
    y[c] = acc;
}

// score[b,n] = v . tanh(sum_4 tP + sum_4 sprojP + tbias + cov*Wc); grid (PN,PB)
__global__ __launch_bounds__(256) void scores_kernel(
    const bf16* __restrict__ tP, const float* __restrict__ sprojP,
    const float* __restrict__ tbias, const void* __restrict__ cov,
    const void* __restrict__ Wc, const void* __restrict__ v,
    const int* __restrict__ flag, float* __restrict__ sc)
{
    const bool in32 = (flag[0] == 0);
    const int n = blockIdx.x, b = blockIdx.y, tid = threadIdx.x;
    __shared__ float red[4];
    const size_t trow = (size_t)(b * PN + n) * PA;
    const float cv = ldin(cov, b * PN + n, in32);
    float s = 0.f;
#pragma unroll
    for (int i = 0; i < 4; ++i) {
        int a = tid + i * 256;
        float tv = 0.f;
#pragma unroll
        for (int p = 0; p < 4; ++p)
            tv += (float)tP[(size_t)p * ((size_t)PM1 * PA) + trow + a];
        float sp = 0.f;
#pragma unroll
        for (int p = 0; p < 4; ++p)
            sp += sprojP[(size_t)p * (PB * PA) + (size_t)b * PA + a];
        s += ldin(v, a, in32) * tanhf(tv + sp + tbias[a] + cv * ldin(Wc, a, in32));
    }
#pragma unroll
    for (int off = 32; off; off >>= 1) s += __shfl_down(s, off);
    if ((tid & 63) == 0) red[tid >> 6] = s;
    __syncthreads();
    if (tid == 0) sc[b * PN + n] = red[0] + red[1] + red[2] + red[3];
}

// softmax(sc[b,:]) inline, wsum[b,g] = sum_n alpha*GFb -> hi/lo; grid (2,PB)
__global__ __launch_bounds__(256) void weighted_kernel(
    const float* __restrict__ sc, const bf16* __restrict__ GFb,
    bf16* __restrict__ whi, bf16* __restrict__ wlo)
{
    const int b = blockIdx.y;
    const int g0 = blockIdx.x * 2048 + threadIdx.x * 8;
    float e[PN];
    float mx = -1e30f;
    for (int n = 0; n < PN; ++n) mx = fmaxf(mx, sc[b * PN + n]);
    float sum = 0.f;
    for (int n = 0; n < PN; ++n) { e[n] = expf(sc[b * PN + n] - mx); sum += e[n]; }
    const float inv = 1.f / sum;
    float acc[8];
#pragma unroll
    for (int j = 0; j < 8; ++j) acc[j] = 0.f;
    for (int n = 0; n < PN; ++n) {
        float al = e[n] * inv;
        bf16x8 gv = *(const bf16x8*)(GFb + (size_t)(b * PN + n) * PG + g0);
#pragma unroll
        for (int j = 0; j < 8; ++j) acc[j] += al * (float)gv[j];
    }
    bf16x8 h, l;
#pragma unroll
    for (int j = 0; j < 8; ++j) {
        h[j] = (bf16)acc[j];
        l[j] = (bf16)(acc[j] - (float)h[j]);
    }
    *(bf16x8*)(whi + (size_t)b * PG + g0) = h;
    *(bf16x8*)(wlo + (size_t)b * PG + g0) = l;
}

// out[b,h] = sum_{z<32} cTP[z][h*PB+b] + cbias[h]; dtype per flag
__global__ __launch_bounds__(256) void final_kernel(
    const float* __restrict__ cTP, const float* __restrict__ cbias,
    const int* __restrict__ flag, void* __restrict__ out)
{
    int i = blockIdx.x * 256 + threadIdx.x;
    int b = i >> 10, h = i & 1023;
    float s = cbias[h];
#pragma unroll
    for (int z = 0; z < 32; ++z) s += cTP[(size_t)z * (PH * PB) + h * PB + b];
    if (flag[0]) ((bf16*)out)[i] = (bf16)s;
    else         ((float*)out)[i] = s;
}

// ---------------------------------------------------------------------------
extern "C" void kernel_launch(void* const* d_in, const int* in_sizes, int n_in,
                              void* d_out, int out_size, void* d_ws, size_t ws_size,
                              hipStream_t stream)
{
    const void* GF  = d_in[0];
    const void* s_t = d_in[1];
    const void* cov = d_in[2];
    const void* Wg  = d_in[3];
    const void* bg  = d_in[4];
    const void* Wgs = d_in[5];
    const void* bgs = d_in[6];
    const void* Wh  = d_in[7];
    const void* Ws  = d_in[8];
    const void* Wc  = d_in[9];
    const void* v   = d_in[10];
    (void)in_sizes; (void)n_in; (void)out_size; (void)ws_size;

    // ---- workspace plan (peak 135 MiB, <= previous 135.5; lifetime-overlap) ----
    // S1 cvt/transpose  S2 biases  S3 Wggs  S4 Wch  S5 t  S6 sproj
    // S7 scores+weighted  S8 cGEMM  S9 final
    const size_t MB = 1u << 20;
    char* W = (char*)d_ws;
    bf16*  GFb    = (bf16*) (W + 0);               // 49 MiB   [S1–S7]
    int*   flag   = (int*)  (W + 52 * MB);
    float* tbias  = (float*)(W + 52 * MB + 4096);
    float* cbias  = (float*)(W + 52 * MB + 8192);
    float* sc     = (float*)(W + 52 * MB + 12288); // 25 KB
    float* mvpart = (float*)(W + 52 * MB + 65536); // 64 KB
    bf16*  s_tb   = (bf16*) (W + 52 * MB + 262144);// 0.25 MiB
    bf16*  WsT    = (bf16*) (W + 53 * MB);         // 2 MiB    [S1–S6]
    bf16*  WhT    = (bf16*) (W + 55 * MB);         // 2 MiB    [S1–S4]
    float* sprojP = (float*)(W + 55 * MB);         // 2 MiB (4 planes) [S6–S7], over dead WhT
    bf16*  WgsT   = (bf16*) (W + 58 * MB);         // 8 MiB    [S1–S3]
    bf16*  Wgb    = (bf16*) (W + 67 * MB);         // 32 MiB   [S1–S3]
    bf16*  WchT   = (bf16*) (W + 67 * MB);         // 8 MiB    [S4–S5], over dead Wgb
    bf16*  tPb    = (bf16*) (W + 76 * MB);         // 49 MiB (4 planes) [S5–S7a]
    bf16*  wsum_hi= (bf16*) (W + 76 * MB);         // 1 MiB    [S7b–S8], over dead tPb
    bf16*  wsum_lo= (bf16*) (W + 77 * MB);         // 1 MiB
    bf16*  WggsS  = (bf16*) (W + 101 * MB);        // 16 MiB (2 planes) [S3; reused S4]
    bf16*  Wggs   = (bf16*) (W + 118 * MB);        // 8 MiB    [S3b–S4] (dead before tPb's tail? no: tPb ends 125 MiB, Wggs dead after S4 — temporal reuse OK)
    bf16*  WggsT  = (bf16*) (W + 127 * MB);        // 8 MiB    [S3b–S8]  peak = 135 MiB
    float* cTP    = (float*)(W + 0);               // 16 MiB (32 planes) [S8–S9], over dead GFb

    dim3 blk(256);

    // 0. dtype detect
    detect_kernel<<<dim3(1), blk, 0, stream>>>((const unsigned short*)GF, flag);

    // 1. conversions / transposes of inputs (Wg now pre-converted to bf16 so
    //    the Wggs GEMM uses the global_load_lds DMA path instead of AADAPT)
    cvt_kernel<<<dim3((PM1 * PG) / 2048), blk, 0, stream>>>(GF, flag, GFb);
    cvt_kernel<<<dim3((PB * PH) / 2048), blk, 0, stream>>>(s_t, flag, s_tb);
    cvt_kernel<<<dim3((PG * PG) / 2048), blk, 0, stream>>>(Wg, flag, Wgb);
    transpose_kernel<<<dim3(PH / 64, PG / 64), blk, 0, stream>>>(Wgs, flag, 0, WgsT, PG, PH);
    transpose_kernel<<<dim3(PA / 64, PH / 64), blk, 0, stream>>>(Wh, flag, 0, WhT, PH, PA);
    transpose_kernel<<<dim3(PA / 64, PH / 64), blk, 0, stream>>>(Ws, flag, 0, WsT, PH, PA);

    // 2. cbias = bg@Wgs + bgs;  tbias = cbias@Wh
    matvec_part_kernel<<<dim3(PH / 256, 16), blk, 0, stream>>>(bg, Wgs, flag, 1, mvpart, PH, PG / 16);
    matvec_fin_kernel<<<dim3(PH / 256), blk, 0, stream>>>(mvpart, bgs, flag, cbias, 16, PH);
    matvec_part_kernel<<<dim3(PA / 256, 16), blk, 0, stream>>>(cbias, Wh, flag, 0, mvpart, PA, PH / 16);
    matvec_fin_kernel<<<dim3(PA / 256), blk, 0, stream>>>(mvpart, nullptr, flag, tbias, 16, PA);

    // 3. Wggs[G,H] = Wg @ Wgs  (bf16 DMA path, split-K 2, bf16 planes)
    //    fused reduce+transpose -> Wggs [G,H] and WggsT [H,G]
    gemm_kernel<1, 0, 1><<<dim3(PH / 128, PG / 128, 2), blk, 0, stream>>>(
        Wgb, WgsT, nullptr, flag, nullptr, WggsS, PG, PH, PG, (PG / 64) / 2);
    transpose_red2_kernel<1><<<dim3(PH / 64, PG / 64), blk, 0, stream>>>(
        WggsS, WggsT, Wggs, PG, PH);

    // 4. Wch[G,A] = Wggs @ Wh  (split-K 2) -> fused reduce+transpose -> WchT[A,G]
    gemm_kernel<1, 0, 1><<<dim3(PA / 128, PG / 128, 2), blk, 0, stream>>>(
        Wggs, WhT, nullptr, flag, nullptr, WggsS, PG, PA, PH, (PH / 64) / 2);
    transpose_red2_kernel<0><<<dim3(PA / 64, PG / 64), blk, 0, stream>>>(
        WggsS, WchT, nullptr, PG, PA);

    // 5. t = GF @ Wch   (split-K 4 -> 1568 blocks ~5 resident/CU, bf16 planes)
    gemm_kernel<1, 0, 1><<<dim3(PA / 128, PM1 / 128, 4), blk, 0, stream>>>(
        GFb, WchT, nullptr, flag, nullptr, tPb, PM1, PA, PG, (PG / 64) / 4);

    // 6. sproj = s_t @ Ws   (split-K 4, fp32 planes)
    gemm_kernel<0, 0, 1><<<dim3(PA / 128, 1, 4), blk, 0, stream>>>(
        s_tb, WsT, nullptr, flag, sprojP, nullptr, PB, PA, PH, (PH / 64) / 4);

    // 7. scores -> softmax+weighted sum (hi/lo)
    scores_kernel<<<dim3(PN, PB), blk, 0, stream>>>(tPb, sprojP, tbias, cov, Wc, v, flag, sc);
    weighted_kernel<<<dim3(PG / 2048, PB), blk, 0, stream>>>(sc, GFb, wsum_hi, wsum_lo);

    // 8. c^T[H,B] = WggsT @ wsum^T  (dual-B hi/lo, split-K 32 -> 256 blocks)
    gemm_kernel<0, 0, 2><<<dim3(1, PH / 128, 32), blk, 0, stream>>>(
        WggsT, wsum_hi, wsum_lo, flag, cTP, nullptr, PH, PB, PG, (PG / 64) / 32);

    // 9. out = c + cbias
    final_kernel<<<dim3((PB * PA) / 256), blk, 0, stream>>>(cTP, cbias, flag, d_out);
}

// Round 2
// 465.994 us; speedup vs baseline: 1.3747x; 1.2126x over previous
//
#include <hip/hip_runtime.h>
#include <cstdint>
#include <cstddef>

typedef __bf16 bf16;
typedef __bf16 bf16x8 __attribute__((ext_vector_type(8)));
typedef __bf16 bf16v4 __attribute__((ext_vector_type(4)));
typedef float  f32x4  __attribute__((ext_vector_type(4)));

// Problem constants: B=128, N=49, G=4096, H=1024, A=1024
#define PB   128
#define PN   49
#define PG   4096
#define PH   1024
#define PA   1024
#define PM1  (PB * PN)   // 6272

// ---------------------------------------------------------------------------
// dtype detect: flag=1 -> bf16 inputs, 0 -> fp32.
// ---------------------------------------------------------------------------
__global__ __launch_bounds__(256) void detect_kernel(
    const unsigned short* __restrict__ raw, int* __restrict__ flag)
{
    __shared__ int cnt;
    if (threadIdx.x == 0) cnt = 0;
    __syncthreads();
    unsigned short u = raw[threadIdx.x];
    float x = __uint_as_float(((unsigned int)u) << 16);
    float a = fabsf(x);
    atomicAdd(&cnt, (a >= 1e-7f && a <= 128.f) ? 1 : 0);
    __syncthreads();
    if (threadIdx.x == 0) flag[0] = (cnt >= 200) ? 1 : 0;
}

__device__ __forceinline__ float ldin(const void* p, size_t i, bool in32) {
    return in32 ? ((const float*)p)[i] : (float)((const bf16*)p)[i];
}

// load 8 consecutive elems of x (fp32 or bf16) as float
__device__ __forceinline__ void ldx8(const void* x, size_t k0, bool in32, float* xv) {
    if (in32) {
        f32x4 lo = *(const f32x4*)((const float*)x + k0);
        f32x4 hi = *(const f32x4*)((const float*)x + k0 + 4);
#pragma unroll
        for (int j = 0; j < 4; ++j) { xv[j] = lo[j]; xv[4 + j] = hi[j]; }
    } else {
        bf16x8 v = *(const bf16x8*)((const bf16*)x + k0);
#pragma unroll
        for (int j = 0; j < 8; ++j) xv[j] = (float)v[j];
    }
}

// raw (flag dtype) -> bf16, 8 elems/thread
__global__ __launch_bounds__(256) void cvt_kernel(
    const void* __restrict__ in, const int* __restrict__ flag,
    bf16* __restrict__ out)
{
    const bool in32 = (flag[0] == 0);
    size_t i = ((size_t)blockIdx.x * 256 + threadIdx.x) * 8;
    bf16x8 o;
    if (in32) {
        f32x4 lo = *(const f32x4*)((const float*)in + i);
        f32x4 hi = *(const f32x4*)((const float*)in + i + 4);
#pragma unroll
        for (int j = 0; j < 4; ++j) { o[j] = (bf16)lo[j]; o[4 + j] = (bf16)hi[j]; }
    } else {
        o = *(const bf16x8*)((const bf16*)in + i);
    }
    *(bf16x8*)(out + i) = o;
}

// ---------------------------------------------------------------------------
// GEMM: C[M,N] = A[M,K] @ (Bt0 [+ Bt1])^T.  128x128 tile, BK=64, 4 waves,
// mfma 16x16x32 bf16.  All operands bf16, staged via global_load_lds(16B)
// async DMA (dest = wave-uniform base + lane*16) with a (chunk+row)&7
// rotation applied on the SOURCE address so frag ds_read_b128 spreads over
// all 8 bank groups (bank-conflict free, verified 0 in rocprof).
// Bijective XCD-aware block swizzle (guide m204) for L2 panel reuse.
// Split-K via bz plane (fp32 Cf or bf16 Cb per BF16OUT).
// ---------------------------------------------------------------------------
template <int BF16OUT, int AADAPT, int BTERMS>
__global__ __launch_bounds__(256, 2) void gemm_kernel(
    const void* __restrict__ Araw, const bf16* __restrict__ Bt0,
    const bf16* __restrict__ Bt1, const int* __restrict__ flag,
    float* __restrict__ Cf, bf16* __restrict__ Cb,
    int M, int N, int K, int kTilesPerSplit)
{
    __shared__ __align__(16) bf16 lds[(BTERMS == 2 ? 3 : 2) * 128 * 64];
    bf16* As  = lds;
    bf16* Bs0 = lds + 128 * 64;
    bf16* Bs1 = lds + 2 * 128 * 64;

    const bool a32 = AADAPT && (flag[0] == 0);

    // ---- bijective XCD swizzle of the flattened block id ----
    const int gx = gridDim.x, gy = gridDim.y;
    const int nwg = gx * gy * (int)gridDim.z;
    int flat = blockIdx.x + gx * (blockIdx.y + gy * blockIdx.z);
    {
        const int q8 = nwg >> 3, r8 = nwg & 7;
        const int xcd = flat & 7, sub = flat >> 3;
        flat = (xcd < r8 ? xcd * (q8 + 1) : r8 * (q8 + 1) + (xcd - r8) * q8) + sub;
    }
    const int bx  = flat % gx;
    const int byz = flat / gx;
    const int by  = byz % gy;
    const int bz  = byz / gy;

    const int tid  = threadIdx.x;
    const int m0   = by * 128;
    const int n0   = bx * 128;
    const int kt0  = bz * kTilesPerSplit;

    const int wave = tid >> 6;
    const int lane = tid & 63;
    const int wm   = (wave >> 1) * 64;
    const int wn   = (wave & 1) * 64;
    const int lm   = lane & 15;
    const int q    = lane >> 4;

    f32x4 acc[4][4];
#pragma unroll
    for (int i = 0; i < 4; ++i)
#pragma unroll
        for (int j = 0; j < 4; ++j) acc[i][j] = (f32x4)0.0f;

    for (int kt = 0; kt < kTilesPerSplit; ++kt) {
        const int k0 = (kt0 + kt) * 64;
#pragma unroll
        for (int it = 0; it < 4; ++it) {
            int p   = it * 256 + tid;
            int row = p >> 3;
            int lc  = ((p & 7) - row) & 7;       // logical chunk held by phys slot p
            size_t offB = (size_t)(n0 + row) * K + k0 + lc * 8;
            __builtin_amdgcn_global_load_lds((void*)(Bt0 + offB), (void*)(Bs0 + p * 8), 16, 0, 0);
            if (BTERMS == 2)
                __builtin_amdgcn_global_load_lds((void*)(Bt1 + offB), (void*)(Bs1 + p * 8), 16, 0, 0);
            size_t offA = (size_t)(m0 + row) * K + k0 + lc * 8;
            if (AADAPT) {
                bf16x8 va;
                if (a32) {
                    const float* pf = (const float*)Araw + offA;
                    f32x4 lo = *(const f32x4*)pf, hi = *(const f32x4*)(pf + 4);
#pragma unroll
                    for (int j = 0; j < 4; ++j) { va[j] = (bf16)lo[j]; va[4 + j] = (bf16)hi[j]; }
                } else {
                    va = *(const bf16x8*)((const bf16*)Araw + offA);
                }
                *(bf16x8*)(As + p * 8) = va;
            } else {
                __builtin_amdgcn_global_load_lds((void*)((const bf16*)Araw + offA),
                                                 (void*)(As + p * 8), 16, 0, 0);
            }
        }
        __syncthreads();

#pragma unroll
        for (int s = 0; s < 2; ++s) {
            bf16x8 af[4], bf0[4], bf1[4];
            const int c = s * 4 + q;
#pragma unroll
            for (int mi = 0; mi < 4; ++mi) {
                int row  = wm + mi * 16 + lm;
                int slot = row * 8 + ((c + row) & 7);
                af[mi] = *(const bf16x8*)(As + slot * 8);
            }
#pragma unroll
            for (int ni = 0; ni < 4; ++ni) {
                int row  = wn + ni * 16 + lm;
                int slot = row * 8 + ((c + row) & 7);
                bf0[ni] = *(const bf16x8*)(Bs0 + slot * 8);
                if (BTERMS == 2) bf1[ni] = *(const bf16x8*)(Bs1 + slot * 8);
            }
#pragma unroll
            for (int mi = 0; mi < 4; ++mi)
#pragma unroll
                for (int ni = 0; ni < 4; ++ni) {
                    acc[mi][ni] = __builtin_amdgcn_mfma_f32_16x16x32_bf16(
                        af[mi], bf0[ni], acc[mi][ni], 0, 0, 0);
                    if (BTERMS == 2)
                        acc[mi][ni] = __builtin_amdgcn_mfma_f32_16x16x32_bf16(
                            af[mi], bf1[ni], acc[mi][ni], 0, 0, 0);
                }
        }
        __syncthreads();
    }

#pragma unroll
    for (int mi = 0; mi < 4; ++mi)
#pragma unroll
        for (int ni = 0; ni < 4; ++ni)
#pragma unroll
            for (int r = 0; r < 4; ++r) {
                int row = m0 + wm + mi * 16 + q * 4 + r;
                int col = n0 + wn + ni * 16 + lm;
                if (BF16OUT)
                    Cb[(size_t)bz * M * N + (size_t)row * N + col] = (bf16)acc[mi][ni][r];
                else
                    Cf[(size_t)bz * M * N + (size_t)row * N + col] = acc[mi][ni][r];
            }
}

// ---------------------------------------------------------------------------
// Transpose [R,C]->[C,R] bf16 out from raw input (dtype per flag).
// grid (C/64, R/64).
// ---------------------------------------------------------------------------
__global__ __launch_bounds__(256) void transpose_kernel(
    const void* __restrict__ in, const int* __restrict__ flag, int inMode,
    bf16* __restrict__ out, int R, int C)
{
    __shared__ bf16 tile[64][65];
    const bool in32 = (inMode == 0) && (flag[0] == 0);
    const int r0 = blockIdx.y * 64, c0 = blockIdx.x * 64;
    const int tx = threadIdx.x & 15, ty = threadIdx.x >> 4;
#pragma unroll
    for (int it = 0; it < 4; ++it) {
        int r = it * 16 + ty;
        size_t base = (size_t)(r0 + r) * C + c0 + tx * 4;
        if (in32) {
            f32x4 v = *(const f32x4*)((const float*)in + base);
#pragma unroll
            for (int i = 0; i < 4; ++i) tile[r][tx * 4 + i] = (bf16)v[i];
        } else {
            bf16v4 v = *(const bf16v4*)((const bf16*)in + base);
#pragma unroll
            for (int i = 0; i < 4; ++i) tile[r][tx * 4 + i] = v[i];
        }
    }
    __syncthreads();
#pragma unroll
    for (int it = 0; it < 4; ++it) {
        int c = it * 16 + ty;
        bf16v4 v;
#pragma unroll
        for (int i = 0; i < 4; ++i) v[i] = tile[tx * 4 + i][c];
        *(bf16v4*)(out + (size_t)(c0 + c) * R + r0 + tx * 4) = v;
    }
}

// ---------------------------------------------------------------------------
// Fused split-K reduce (2 bf16 planes) + transpose.
// in: two bf16 planes [R,C] at in and in+R*C.  outT[C,R] = (p0+p1)^T.
// WRITEN: also write outN[R,C] = p0+p1.  grid (C/64, R/64).
// ---------------------------------------------------------------------------
template <int WRITEN>
__global__ __launch_bounds__(256) void transpose_red2_kernel(
    const bf16* __restrict__ in, bf16* __restrict__ outT,
    bf16* __restrict__ outN, int R, int C)
{
    __shared__ bf16 tile[64][65];
    const size_t plane = (size_t)R * C;
    const int r0 = blockIdx.y * 64, c0 = blockIdx.x * 64;
    const int tx = threadIdx.x & 15, ty = threadIdx.x >> 4;
#pragma unroll
    for (int it = 0; it < 4; ++it) {
        int r = it * 16 + ty;
        size_t base = (size_t)(r0 + r) * C + c0 + tx * 4;
        bf16v4 va = *(const bf16v4*)(in + base);
        bf16v4 vb = *(const bf16v4*)(in + plane + base);
        bf16v4 s4;
#pragma unroll
        for (int i = 0; i < 4; ++i) {
            s4[i] = (bf16)((float)va[i] + (float)vb[i]);
            tile[r][tx * 4 + i] = s4[i];
        }
        if (WRITEN) *(bf16v4*)(outN + base) = s4;
    }
    __syncthreads();
#pragma unroll
    for (int it = 0; it < 4; ++it) {
        int c = it * 16 + ty;
        bf16v4 v;
#pragma unroll
        for (int i = 0; i < 4; ++i) v[i] = tile[tx * 4 + i][c];
        *(bf16v4*)(outT + (size_t)(c0 + c) * R + r0 + tx * 4) = v;
    }
}

// ---------------------------------------------------------------------------
// rowdot: y[c] = sum_k x[k] * Wt[c,k] (+ addv[c]).  Wt is a bf16 transposed
// weight [C,K] (row-contiguous dots).  One WAVE per output element: bf16x8
// vector loads (512 elems/wave/iter), shfl tree reduce.  Replaces the serial
// matvec_part/fin chain (85 us @ 1.2% HBM -> ~7 us coalesced).
// xMode 0: x is fp32 ws buffer; xMode 1: x is raw input (dtype per flag).
// grid (C/4), block 256.
// ---------------------------------------------------------------------------
__global__ __launch_bounds__(256) void rowdot_kernel(
    const void* __restrict__ x, const bf16* __restrict__ Wt,
    const void* __restrict__ addv, const int* __restrict__ flag, int xMode,
    float* __restrict__ y, int K)
{
    const bool raw32 = (flag[0] == 0);
    const bool x32   = (xMode == 0) || raw32;
    const int wave = threadIdx.x >> 6, lane = threadIdx.x & 63;
    const int c = blockIdx.x * 4 + wave;
    float s = 0.f;
    for (int k0 = lane * 8; k0 < K; k0 += 512) {
        bf16x8 w = *(const bf16x8*)(Wt + (size_t)c * K + k0);
        float xv[8];
        ldx8(x, (size_t)k0, x32, xv);
#pragma unroll
        for (int j = 0; j < 8; ++j) s += xv[j] * (float)w[j];
    }
#pragma unroll
    for (int off = 32; off; off >>= 1) s += __shfl_down(s, off);
    if (lane == 0) {
        float a = addv ? ldin(addv, c, raw32) : 0.f;
        y[c] = s + a;
    }
}

// score[b,n] = v . tanh(sum_4 tP + sum_4 sprojP + tbias + cov*Wc); grid (PN,PB)
__global__ __launch_bounds__(256) void scores_kernel(
    const bf16* __restrict__ tP, const float* __restrict__ sprojP,
    const float* __restrict__ tbias, const void* __restrict__ cov,
    const void* __restrict__ Wc, const void* __restrict__ v,
    const int* __restrict__ flag, float* __restrict__ sc)
{
    const bool in32 = (flag[0] == 0);
    const int n = blockIdx.x, b = blockIdx.y, tid = threadIdx.x;
    __shared__ float red[4];
    const size_t trow = (size_t)(b * PN + n) * PA;
    const float cv = ldin(cov, b * PN + n, in32);
    float s = 0.f;
#pragma unroll
    for (int i = 0; i < 4; ++i) {
        int a = tid + i * 256;
        float tv = 0.f;
#pragma unroll
        for (int p = 0; p < 4; ++p)
            tv += (float)tP[(size_t)p * ((size_t)PM1 * PA) + trow + a];
        float sp = 0.f;
#pragma unroll
        for (int p = 0; p < 4; ++p)
            sp += sprojP[(size_t)p * (PB * PA) + (size_t)b * PA + a];
        s += ldin(v, a, in32) * tanhf(tv + sp + tbias[a] + cv * ldin(Wc, a, in32));
    }
#pragma unroll
    for (int off = 32; off; off >>= 1) s += __shfl_down(s, off);
    if ((tid & 63) == 0) red[tid >> 6] = s;
    __syncthreads();
    if (tid == 0) sc[b * PN + n] = red[0] + red[1] + red[2] + red[3];
}

// softmax(sc[b,:]) inline, wsum[b,g] = sum_n alpha*GFb -> hi/lo; grid (2,PB)
__global__ __launch_bounds__(256) void weighted_kernel(
    const float* __restrict__ sc, const bf16* __restrict__ GFb,
    bf16* __restrict__ whi, bf16* __restrict__ wlo)
{
    const int b = blockIdx.y;
    const int g0 = blockIdx.x * 2048 + threadIdx.x * 8;
    float e[PN];
    float mx = -1e30f;
    for (int n = 0; n < PN; ++n) mx = fmaxf(mx, sc[b * PN + n]);
    float sum = 0.f;
    for (int n = 0; n < PN; ++n) { e[n] = expf(sc[b * PN + n] - mx); sum += e[n]; }
    const float inv = 1.f / sum;
    float acc[8];
#pragma unroll
    for (int j = 0; j < 8; ++j) acc[j] = 0.f;
    for (int n = 0; n < PN; ++n) {
        float al = e[n] * inv;
        bf16x8 gv = *(const bf16x8*)(GFb + (size_t)(b * PN + n) * PG + g0);
#pragma unroll
        for (int j = 0; j < 8; ++j) acc[j] += al * (float)gv[j];
    }
    bf16x8 h, l;
#pragma unroll
    for (int j = 0; j < 8; ++j) {
        h[j] = (bf16)acc[j];
        l[j] = (bf16)(acc[j] - (float)h[j]);
    }
    *(bf16x8*)(whi + (size_t)b * PG + g0) = h;
    *(bf16x8*)(wlo + (size_t)b * PG + g0) = l;
}

// out[b,h] = sum_{z<32} cTP[z][h*PB+b] + cbias[h]; dtype per flag
__global__ __launch_bounds__(256) void final_kernel(
    const float* __restrict__ cTP, const float* __restrict__ cbias,
    const int* __restrict__ flag, void* __restrict__ out)
{
    int i = blockIdx.x * 256 + threadIdx.x;
    int b = i >> 10, h = i & 1023;
    float s = cbias[h];
#pragma unroll
    for (int z = 0; z < 32; ++z) s += cTP[(size_t)z * (PH * PB) + h * PB + b];
    if (flag[0]) ((bf16*)out)[i] = (bf16)s;
    else         ((float*)out)[i] = s;
}

// ---------------------------------------------------------------------------
extern "C" void kernel_launch(void* const* d_in, const int* in_sizes, int n_in,
                              void* d_out, int out_size, void* d_ws, size_t ws_size,
                              hipStream_t stream)
{
    const void* GF  = d_in[0];
    const void* s_t = d_in[1];
    const void* cov = d_in[2];
    const void* Wg  = d_in[3];
    const void* bg  = d_in[4];
    const void* Wgs = d_in[5];
    const void* bgs = d_in[6];
    const void* Wh  = d_in[7];
    const void* Ws  = d_in[8];
    const void* Wc  = d_in[9];
    const void* v   = d_in[10];
    (void)in_sizes; (void)n_in; (void)out_size; (void)ws_size;

    // ---- workspace plan (peak 135 MiB; lifetime-overlap) ----
    const size_t MB = 1u << 20;
    char* W = (char*)d_ws;
    bf16*  GFb    = (bf16*) (W + 0);               // 49 MiB   [S1-S7]
    int*   flag   = (int*)  (W + 52 * MB);
    float* tbias  = (float*)(W + 52 * MB + 4096);
    float* cbias  = (float*)(W + 52 * MB + 8192);
    float* sc     = (float*)(W + 52 * MB + 12288); // 25 KB
    bf16*  s_tb   = (bf16*) (W + 52 * MB + 262144);// 0.25 MiB
    bf16*  WsT    = (bf16*) (W + 53 * MB);         // 2 MiB    [S1-S6]
    bf16*  WhT    = (bf16*) (W + 55 * MB);         // 2 MiB    [S1-S4]
    float* sprojP = (float*)(W + 55 * MB);         // 2 MiB (4 planes) [S6-S7], over dead WhT
    bf16*  WgsT   = (bf16*) (W + 58 * MB);         // 8 MiB    [S1-S3]
    bf16*  Wgb    = (bf16*) (W + 67 * MB);         // 32 MiB   [S1-S3]
    bf16*  WchT   = (bf16*) (W + 67 * MB);         // 8 MiB    [S4-S5], over dead Wgb
    bf16*  tPb    = (bf16*) (W + 76 * MB);         // 49 MiB (4 planes) [S5-S7a]
    bf16*  wsum_hi= (bf16*) (W + 76 * MB);         // 1 MiB    [S7b-S8], over dead tPb
    bf16*  wsum_lo= (bf16*) (W + 77 * MB);         // 1 MiB
    bf16*  WggsS  = (bf16*) (W + 101 * MB);        // 16 MiB (2 planes) [S3; reused S4]
    bf16*  Wggs   = (bf16*) (W + 118 * MB);        // 8 MiB    [S3b-S4]
    bf16*  WggsT  = (bf16*) (W + 127 * MB);        // 8 MiB    [S3b-S8]  peak = 135 MiB
    float* cTP    = (float*)(W + 0);               // 16 MiB (32 planes) [S8-S9], over dead GFb

    dim3 blk(256);

    // 0. dtype detect
    detect_kernel<<<dim3(1), blk, 0, stream>>>((const unsigned short*)GF, flag);

    // 1. conversions / transposes of inputs
    cvt_kernel<<<dim3((PM1 * PG) / 2048), blk, 0, stream>>>(GF, flag, GFb);
    cvt_kernel<<<dim3((PB * PH) / 2048), blk, 0, stream>>>(s_t, flag, s_tb);
    cvt_kernel<<<dim3((PG * PG) / 2048), blk, 0, stream>>>(Wg, flag, Wgb);
    transpose_kernel<<<dim3(PH / 64, PG / 64), blk, 0, stream>>>(Wgs, flag, 0, WgsT, PG, PH);
    transpose_kernel<<<dim3(PA / 64, PH / 64), blk, 0, stream>>>(Wh, flag, 0, WhT, PH, PA);
    transpose_kernel<<<dim3(PA / 64, PH / 64), blk, 0, stream>>>(Ws, flag, 0, WsT, PH, PA);

    // 2. cbias = bg@Wgs + bgs;  tbias = cbias@Wh   (wave-per-output rowdots
    //    on the bf16 transposed weights; replaces serial matvec chain)
    rowdot_kernel<<<dim3(PH / 4), blk, 0, stream>>>(bg, WgsT, bgs, flag, 1, cbias, PG);
    rowdot_kernel<<<dim3(PA / 4), blk, 0, stream>>>(cbias, WhT, nullptr, flag, 0, tbias, PH);

    // 3. Wggs[G,H] = Wg @ Wgs  (bf16 DMA path, split-K 2, bf16 planes)
    //    fused reduce+transpose -> Wggs [G,H] and WggsT [H,G]
    gemm_kernel<1, 0, 1><<<dim3(PH / 128, PG / 128, 2), blk, 0, stream>>>(
        Wgb, WgsT, nullptr, flag, nullptr, WggsS, PG, PH, PG, (PG / 64) / 2);
    transpose_red2_kernel<1><<<dim3(PH / 64, PG / 64), blk, 0, stream>>>(
        WggsS, WggsT, Wggs, PG, PH);

    // 4. Wch[G,A] = Wggs @ Wh  (split-K 2) -> fused reduce+transpose -> WchT[A,G]
    gemm_kernel<1, 0, 1><<<dim3(PA / 128, PG / 128, 2), blk, 0, stream>>>(
        Wggs, WhT, nullptr, flag, nullptr, WggsS, PG, PA, PH, (PH / 64) / 2);
    transpose_red2_kernel<0><<<dim3(PA / 64, PG / 64), blk, 0, stream>>>(
        WggsS, WchT, nullptr, PG, PA);

    // 5. t = GF @ Wch   (split-K 4 -> 1568 blocks, bf16 planes)
    gemm_kernel<1, 0, 1><<<dim3(PA / 128, PM1 / 128, 4), blk, 0, stream>>>(
        GFb, WchT, nullptr, flag, nullptr, tPb, PM1, PA, PG, (PG / 64) / 4);

    // 6. sproj = s_t @ Ws   (split-K 4, fp32 planes)
    gemm_kernel<0, 0, 1><<<dim3(PA / 128, 1, 4), blk, 0, stream>>>(
        s_tb, WsT, nullptr, flag, sprojP, nullptr, PB, PA, PH, (PH / 64) / 4);

    // 7. scores -> softmax+weighted sum (hi/lo)
    scores_kernel<<<dim3(PN, PB), blk, 0, stream>>>(tPb, sprojP, tbias, cov, Wc, v, flag, sc);
    weighted_kernel<<<dim3(PG / 2048, PB), blk, 0, stream>>>(sc, GFb, wsum_hi, wsum_lo);

    // 8. c^T[H,B] = WggsT @ wsum^T  (dual-B hi/lo, split-K 32 -> 256 blocks)
    gemm_kernel<0, 0, 2><<<dim3(1, PH / 128, 32), blk, 0, stream>>>(
        WggsT, wsum_hi, wsum_lo, flag, cTP, nullptr, PH, PB, PG, (PG / 64) / 32);

    // 9. out = c + cbias
    final_kernel<<<dim3((PB * PA) / 256), blk, 0, stream>>>(cTP, cbias, flag, d_out);
}